// Round 1
// baseline (1798.878 us; speedup 1.0000x reference)
//
#include <hip/hip_runtime.h>

// Problem: QINCoStep — bs=2048, d=128, K=256, h=256, all fp32.
// ws layout (floats):
//   0       WzT   128*128   (WzT[j][d] = Wc[d][j])
//   16384   WxT   128*128   (WxT[j][d] = Wc[d][128+j])
//   32768   W1T0  128*256   (W1T[d][h] = W1[h][d])
//   65536   W2T0  256*128   (W2T[h][i] = W2[i][h])
//   98304   W1T1  128*256
//   131072  W2T1  256*128
//   163840  z0    256*128
//   196608  u     2048*128
//   458752  dist  2048*256
//   983040  codes (int32) 2048
// total 985088 floats ~= 3.94 MB of ws.

__global__ __launch_bounds__(256) void k_transpose(
    const float* __restrict__ Wc,
    const float* __restrict__ W1a, const float* __restrict__ W2a,
    const float* __restrict__ W1b, const float* __restrict__ W2b,
    float* __restrict__ WzT, float* __restrict__ WxT,
    float* __restrict__ W1Ta, float* __restrict__ W2Ta,
    float* __restrict__ W1Tb, float* __restrict__ W2Tb)
{
    int g = blockIdx.x * 256 + threadIdx.x;   // 0 .. 163839
    if (g < 16384) {                          // WzT[j][d] = Wc[d][j]
        int j = g >> 7, d = g & 127;
        WzT[g] = Wc[d * 256 + j];
    } else if (g < 32768) {                   // WxT[j][d] = Wc[d][128+j]
        int e = g - 16384; int j = e >> 7, d = e & 127;
        WxT[e] = Wc[d * 256 + 128 + j];
    } else if (g < 65536) {                   // W1Ta[d][h] = W1a[h][d]
        int e = g - 32768; int d = e >> 8, h = e & 255;
        W1Ta[e] = W1a[h * 128 + d];
    } else if (g < 98304) {                   // W2Ta[h][i] = W2a[i][h]
        int e = g - 65536; int h = e >> 7, i = e & 127;
        W2Ta[e] = W2a[i * 256 + h];
    } else if (g < 131072) {
        int e = g - 98304; int d = e >> 8, h = e & 255;
        W1Tb[e] = W1b[h * 128 + d];
    } else if (g < 163840) {
        int e = g - 131072; int h = e >> 7, i = e & 127;
        W2Tb[e] = W2b[i * 256 + h];
    }
}

// z0[k][d] = bc[d] + cb[k][d] + sum_j cb[k][j] * Wz[d][j]   (Wz[d][j]=Wc[d][j])
__global__ __launch_bounds__(256) void k_z0(
    const float* __restrict__ cb, const float* __restrict__ bc,
    const float* __restrict__ WzT, float* __restrict__ z0)
{
    int g = blockIdx.x * 256 + threadIdx.x;   // 0..32767
    int k = g >> 7, d = g & 127;
    float acc = bc[d] + cb[k * 128 + d];
    for (int j = 0; j < 128; ++j)
        acc = fmaf(cb[k * 128 + j], WzT[j * 128 + d], acc);
    z0[g] = acc;
}

// u[b][d] = sum_j xhat[b][j] * Wx[d][j]   (Wx[d][j]=Wc[d][128+j])
__global__ __launch_bounds__(256) void k_u(
    const float* __restrict__ xhat, const float* __restrict__ WxT,
    float* __restrict__ u)
{
    int g = blockIdx.x * 256 + threadIdx.x;   // 0..262143
    int bl = g >> 7, d = g & 127;
    const float* xr = xhat + bl * 128;
    float acc = 0.f;
    for (int j = 0; j < 128; ++j)
        acc = fmaf(xr[j], WxT[j * 128 + d], acc);
    u[g] = acc;
}

// Main pass: per workgroup one b and a 32-code tile; run both MLP blocks on the
// 32x128 z tile in LDS and emit only dist[b][k].
__global__ __launch_bounds__(256) void k_dist(
    const float* __restrict__ z0, const float* __restrict__ u,
    const float* __restrict__ xhat, const float* __restrict__ x,
    const float* __restrict__ W1Ta, const float* __restrict__ W2Ta,
    const float* __restrict__ W1Tb, const float* __restrict__ W2Tb,
    float* __restrict__ dist)
{
    __shared__ float zt[32][128];    // 16 KB
    __shared__ float ht[32][256];    // 32 KB
    __shared__ float diffv[128];
    __shared__ float part[32][8];
    const int t  = threadIdx.x;
    const int b  = blockIdx.x >> 3;
    const int k0 = (blockIdx.x & 7) * 32;

    if (t < 128) diffv[t] = xhat[b * 128 + t] - x[b * 128 + t];
#pragma unroll
    for (int n = 0; n < 16; ++n) {
        int e = n * 256 + t; int k = e >> 7, d = e & 127;
        zt[k][d] = z0[(k0 + k) * 128 + d] + u[b * 128 + d];
    }
    __syncthreads();

    const float* W1T = W1Ta; const float* W2T = W2Ta;
#pragma unroll 1
    for (int blk = 0; blk < 2; ++blk) {
        // GEMM1: ht = relu(zt @ W1^T); thread -> 8 k-rows x 4 h-cols
        {
            const int kg = (t >> 6) * 8;
            const int c0 = (t & 63) * 4;
            float acc[8][4];
#pragma unroll
            for (int j = 0; j < 8; ++j) { acc[j][0] = 0.f; acc[j][1] = 0.f; acc[j][2] = 0.f; acc[j][3] = 0.f; }
#pragma unroll 4
            for (int d = 0; d < 128; ++d) {
                const float4 w = *(const float4*)(W1T + d * 256 + c0);
#pragma unroll
                for (int j = 0; j < 8; ++j) {
                    const float zv = zt[kg + j][d];      // LDS broadcast
                    acc[j][0] = fmaf(zv, w.x, acc[j][0]);
                    acc[j][1] = fmaf(zv, w.y, acc[j][1]);
                    acc[j][2] = fmaf(zv, w.z, acc[j][2]);
                    acc[j][3] = fmaf(zv, w.w, acc[j][3]);
                }
            }
#pragma unroll
            for (int j = 0; j < 8; ++j) {
                float4 r;
                r.x = fmaxf(acc[j][0], 0.f);
                r.y = fmaxf(acc[j][1], 0.f);
                r.z = fmaxf(acc[j][2], 0.f);
                r.w = fmaxf(acc[j][3], 0.f);
                *(float4*)&ht[kg + j][c0] = r;
            }
        }
        __syncthreads();
        // GEMM2: zt += ht @ W2^T; thread -> 4 k-rows x 4 i-cols
        {
            const int i0 = (t & 31) * 4;
            const int kq = (t >> 5) * 4;
            float acc[4][4];
#pragma unroll
            for (int j = 0; j < 4; ++j) { acc[j][0] = 0.f; acc[j][1] = 0.f; acc[j][2] = 0.f; acc[j][3] = 0.f; }
#pragma unroll 4
            for (int h = 0; h < 256; ++h) {
                const float4 w = *(const float4*)(W2T + h * 128 + i0);
#pragma unroll
                for (int j = 0; j < 4; ++j) {
                    const float hv = ht[kq + j][h];      // 2-way LDS broadcast (free)
                    acc[j][0] = fmaf(hv, w.x, acc[j][0]);
                    acc[j][1] = fmaf(hv, w.y, acc[j][1]);
                    acc[j][2] = fmaf(hv, w.z, acc[j][2]);
                    acc[j][3] = fmaf(hv, w.w, acc[j][3]);
                }
            }
#pragma unroll
            for (int j = 0; j < 4; ++j) {
                zt[kq + j][i0 + 0] += acc[j][0];
                zt[kq + j][i0 + 1] += acc[j][1];
                zt[kq + j][i0 + 2] += acc[j][2];
                zt[kq + j][i0 + 3] += acc[j][3];
            }
        }
        __syncthreads();
        W1T = W1Tb; W2T = W2Tb;
    }

    // dist[k] = sum_d (zt[k][d] + xhat[d] - x[d])^2
    {
        const int k = t >> 3, d0 = (t & 7) * 16;
        float s = 0.f;
#pragma unroll
        for (int n = 0; n < 16; ++n) {
            const float v = zt[k][d0 + n] + diffv[d0 + n];
            s = fmaf(v, v, s);
        }
        part[k][t & 7] = s;
    }
    __syncthreads();
    if (t < 32) {
        float s = 0.f;
#pragma unroll
        for (int n = 0; n < 8; ++n) s += part[t][n];
        dist[b * 256 + k0 + t] = s;
    }
}

// argmin over 256 codes per row; ties -> lowest index (numpy semantics).
// codes written as float32 into d_out[0:2048] and as int into ws for k_final.
__global__ __launch_bounds__(256) void k_argmin(
    const float* __restrict__ dist, int* __restrict__ codes,
    float* __restrict__ out0)
{
    __shared__ float sv[256];
    __shared__ int   si[256];
    const int t = threadIdx.x, b = blockIdx.x;
    sv[t] = dist[b * 256 + t]; si[t] = t;
    __syncthreads();
    for (int s = 128; s > 0; s >>= 1) {
        if (t < s) {
            float v2 = sv[t + s]; int i2 = si[t + s];
            if (v2 < sv[t] || (v2 == sv[t] && i2 < si[t])) { sv[t] = v2; si[t] = i2; }
        }
        __syncthreads();
    }
    if (t == 0) { codes[b] = si[0]; out0[b] = (float)si[0]; }
}

// Recompute z for the 2048 winning rows only (8 rows per workgroup).
// delta = cand - xhat = z_final.
__global__ __launch_bounds__(256) void k_final(
    const float* __restrict__ z0, const float* __restrict__ u,
    const int* __restrict__ codes,
    const float* __restrict__ W1Ta, const float* __restrict__ W2Ta,
    const float* __restrict__ W1Tb, const float* __restrict__ W2Tb,
    float* __restrict__ outd)   // = d_out + 2048
{
    __shared__ float z8[8][128];
    __shared__ float h8[8][256];
    __shared__ int ci[8];
    const int t = threadIdx.x;
    const int b0 = blockIdx.x * 8;
    if (t < 8) ci[t] = codes[b0 + t];
    __syncthreads();
#pragma unroll
    for (int n = 0; n < 4; ++n) {
        int e = n * 256 + t; int r = e >> 7, d = e & 127;
        z8[r][d] = z0[ci[r] * 128 + d] + u[(b0 + r) * 128 + d];
    }
    __syncthreads();
    const float* W1T = W1Ta; const float* W2T = W2Ta;
#pragma unroll 1
    for (int blk = 0; blk < 2; ++blk) {
        float a1[8] = {0.f,0.f,0.f,0.f,0.f,0.f,0.f,0.f};
        for (int d = 0; d < 128; ++d) {
            const float w = W1T[d * 256 + t];            // coalesced
#pragma unroll
            for (int r = 0; r < 8; ++r) a1[r] = fmaf(z8[r][d], w, a1[r]);
        }
#pragma unroll
        for (int r = 0; r < 8; ++r) h8[r][t] = fmaxf(a1[r], 0.f);
        __syncthreads();
        const int ig = t & 127, rg = (t >> 7) * 4;
        float a2[4] = {0.f,0.f,0.f,0.f};
        for (int h = 0; h < 256; ++h) {
            const float w = W2T[h * 128 + ig];           // coalesced
#pragma unroll
            for (int j = 0; j < 4; ++j) a2[j] = fmaf(h8[rg + j][h], w, a2[j]);
        }
        __syncthreads();
#pragma unroll
        for (int j = 0; j < 4; ++j) z8[rg + j][ig] += a2[j];
        __syncthreads();
        W1T = W1Tb; W2T = W2Tb;
    }
#pragma unroll
    for (int n = 0; n < 4; ++n) {
        int e = n * 256 + t; int r = e >> 7, d = e & 127;
        outd[(b0 + r) * 128 + d] = z8[r][d];
    }
}

extern "C" void kernel_launch(void* const* d_in, const int* in_sizes, int n_in,
                              void* d_out, int out_size, void* d_ws, size_t ws_size,
                              hipStream_t stream) {
    const float* xhat = (const float*)d_in[0];
    const float* x    = (const float*)d_in[1];
    const float* cb   = (const float*)d_in[2];
    const float* Wc   = (const float*)d_in[3];
    const float* bc   = (const float*)d_in[4];
    const float* W1_0 = (const float*)d_in[5];
    const float* W2_0 = (const float*)d_in[6];
    const float* W1_1 = (const float*)d_in[7];
    const float* W2_1 = (const float*)d_in[8];
    float* out = (float*)d_out;
    float* ws  = (float*)d_ws;

    float* WzT  = ws + 0;
    float* WxT  = ws + 16384;
    float* W1T0 = ws + 32768;
    float* W2T0 = ws + 65536;
    float* W1T1 = ws + 98304;
    float* W2T1 = ws + 131072;
    float* z0   = ws + 163840;
    float* u    = ws + 196608;
    float* dist = ws + 458752;
    int*   codes = (int*)(ws + 983040);

    k_transpose<<<640, 256, 0, stream>>>(Wc, W1_0, W2_0, W1_1, W2_1,
                                         WzT, WxT, W1T0, W2T0, W1T1, W2T1);
    k_z0<<<128, 256, 0, stream>>>(cb, bc, WzT, z0);
    k_u<<<1024, 256, 0, stream>>>(xhat, WxT, u);
    k_dist<<<16384, 256, 0, stream>>>(z0, u, xhat, x, W1T0, W2T0, W1T1, W2T1, dist);
    k_argmin<<<2048, 256, 0, stream>>>(dist, codes, out);
    k_final<<<256, 256, 0, stream>>>(z0, u, codes, W1T0, W2T0, W1T1, W2T1, out + 2048);
}

// Round 2
// 596.926 us; speedup vs baseline: 3.0136x; 3.0136x over previous
//
#include <hip/hip_runtime.h>

// QINCoStep — bs=2048, d=128, K=256, h=256, fp32 in/out.
// Round 2: MLP GEMMs on MFMA 32x32x16 bf16 with hi/lo split (3 products),
// transposed formulation (A = static weights prepacked as fragments,
// B = z/h from LDS, D accumulates z-state in registers).
//
// ws layout (floats):
//   0       WzT   128*128     16384  WxT   128*128
//   32768   W1T0  128*256     65536  W2T0  256*128
//   98304   W1T1  128*256     131072 W2T1  256*128
//   163840  z0    256*128     196608 u     2048*128
//   458752  dist  2048*256    983040 codes (int32) 2048
//   985088  frag region: 32768 uint4 (512 KB): W1f0, W2f0, W1f1, W2f1 (8192 uint4 each)

typedef short bf8_t __attribute__((ext_vector_type(8)));
typedef float f32x16 __attribute__((ext_vector_type(16)));

__device__ inline unsigned short f2bh(float x) {
    unsigned u = __float_as_uint(x);
    u += 0x7fffu + ((u >> 16) & 1u);
    return (unsigned short)(u >> 16);
}
__device__ inline float bh2f(unsigned short h) {
    return __uint_as_float(((unsigned)h) << 16);
}
__device__ inline f32x16 mfma_bf(uint4 a, uint4 b, f32x16 c) {
    bf8_t av = __builtin_bit_cast(bf8_t, a);
    bf8_t bv = __builtin_bit_cast(bf8_t, b);
    return __builtin_amdgcn_mfma_f32_32x32x16_bf16(av, bv, c, 0, 0, 0);
}

// ---------------- prep kernels (tiny) ----------------

__global__ __launch_bounds__(256) void k_transpose(
    const float* __restrict__ Wc,
    const float* __restrict__ W1a, const float* __restrict__ W2a,
    const float* __restrict__ W1b, const float* __restrict__ W2b,
    float* __restrict__ WzT, float* __restrict__ WxT,
    float* __restrict__ W1Ta, float* __restrict__ W2Ta,
    float* __restrict__ W1Tb, float* __restrict__ W2Tb)
{
    int g = blockIdx.x * 256 + threadIdx.x;   // 0 .. 163839
    if (g < 16384) {
        int j = g >> 7, d = g & 127;
        WzT[g] = Wc[d * 256 + j];
    } else if (g < 32768) {
        int e = g - 16384; int j = e >> 7, d = e & 127;
        WxT[e] = Wc[d * 256 + 128 + j];
    } else if (g < 65536) {
        int e = g - 32768; int d = e >> 8, h = e & 255;
        W1Ta[e] = W1a[h * 128 + d];
    } else if (g < 98304) {
        int e = g - 65536; int h = e >> 7, i = e & 127;
        W2Ta[e] = W2a[i * 256 + h];
    } else if (g < 131072) {
        int e = g - 98304; int d = e >> 8, h = e & 255;
        W1Tb[e] = W1b[h * 128 + d];
    } else if (g < 163840) {
        int e = g - 131072; int h = e >> 7, i = e & 127;
        W2Tb[e] = W2b[i * 256 + h];
    }
}

// Pack W1_blk [256][128] and W2_blk [128][256] into A-fragments (hi/lo bf16)
// for mfma 32x32x16: lane -> row m = 32*mt + (lane&31), cols 16*kt + 8*(lane>>5) + j.
// Layout (uint4): mat*8192 + tile*128 + s*64 + lane, tile = mt*NKT + kt.
__global__ __launch_bounds__(256) void k_pack(
    const float* __restrict__ W1a, const float* __restrict__ W2a,
    const float* __restrict__ W1b, const float* __restrict__ W2b,
    uint4* __restrict__ F)
{
    int idx = blockIdx.x * 256 + threadIdx.x;   // 0..16383
    int mat = idx >> 12, fp = idx & 4095;
    int tile = fp >> 6, lane = fp & 63;
    const float* src;
    if (mat == 0 || mat == 2) {                 // W1-type: [256][128], 8 mt x 8 kt
        const float* W = (mat == 0) ? W1a : W1b;
        int mt = tile >> 3, kt = tile & 7;
        int m = 32 * mt + (lane & 31);
        int c0 = 16 * kt + 8 * ((lane >> 5) & 1);
        src = W + m * 128 + c0;
    } else {                                    // W2-type: [128][256], 4 mt x 16 kt
        const float* W = (mat == 1) ? W2a : W2b;
        int mt = tile >> 4, kt = tile & 15;
        int m = 32 * mt + (lane & 31);
        int c0 = 16 * kt + 8 * ((lane >> 5) & 1);
        src = W + m * 256 + c0;
    }
    unsigned short hs[8], ls[8];
#pragma unroll
    for (int j = 0; j < 8; ++j) {
        float v = src[j];
        unsigned short h = f2bh(v);
        hs[j] = h;
        ls[j] = f2bh(v - bh2f(h));
    }
    uint4 hv, lv;
    hv.x = (unsigned)hs[0] | ((unsigned)hs[1] << 16);
    hv.y = (unsigned)hs[2] | ((unsigned)hs[3] << 16);
    hv.z = (unsigned)hs[4] | ((unsigned)hs[5] << 16);
    hv.w = (unsigned)hs[6] | ((unsigned)hs[7] << 16);
    lv.x = (unsigned)ls[0] | ((unsigned)ls[1] << 16);
    lv.y = (unsigned)ls[2] | ((unsigned)ls[3] << 16);
    lv.z = (unsigned)ls[4] | ((unsigned)ls[5] << 16);
    lv.w = (unsigned)ls[6] | ((unsigned)ls[7] << 16);
    uint4* dst = F + mat * 8192 + tile * 128;
    dst[lane] = hv;
    dst[64 + lane] = lv;
}

__global__ __launch_bounds__(256) void k_z0(
    const float* __restrict__ cb, const float* __restrict__ bc,
    const float* __restrict__ WzT, float* __restrict__ z0)
{
    int g = blockIdx.x * 256 + threadIdx.x;   // 0..32767
    int k = g >> 7, d = g & 127;
    float acc = bc[d] + cb[k * 128 + d];
    for (int j = 0; j < 128; ++j)
        acc = fmaf(cb[k * 128 + j], WzT[j * 128 + d], acc);
    z0[g] = acc;
}

__global__ __launch_bounds__(256) void k_u(
    const float* __restrict__ xhat, const float* __restrict__ WxT,
    float* __restrict__ u)
{
    int g = blockIdx.x * 256 + threadIdx.x;   // 0..262143
    int bl = g >> 7, d = g & 127;
    const float* xr = xhat + bl * 128;
    float acc = 0.f;
    for (int j = 0; j < 128; ++j)
        acc = fmaf(xr[j], WxT[j * 128 + d], acc);
    u[g] = acc;
}

// ---------------- main MFMA dist kernel ----------------
// wg: 4 waves, one b, 64 codes. Transposed GEMMs, h chunked by 64.
// Wave grid 2x2: wm = d/h-dim half, wn = k-code half (32 codes).
__global__ __launch_bounds__(256, 3) void k_dist_mfma(
    const float* __restrict__ z0, const float* __restrict__ u,
    const float* __restrict__ xhat, const float* __restrict__ x,
    const uint4* __restrict__ W1f0, const uint4* __restrict__ W2f0,
    const uint4* __restrict__ W1f1, const uint4* __restrict__ W2f1,
    float* __restrict__ dist)
{
    __shared__ unsigned short Zh[64][136], Zl[64][136];   // z hi/lo, [k][d], pad 8
    __shared__ unsigned short Hh[64][72],  Hl[64][72];    // h chunk hi/lo, [k][h]
    __shared__ float diffv[128];
    __shared__ float part[2][64];

    const int t = threadIdx.x;
    const int b  = blockIdx.x >> 2;
    const int k0 = (blockIdx.x & 3) << 6;
    const int lane = t & 63, wave = t >> 6;
    const int wm = wave >> 1, wn = wave & 1;
    const int l31 = lane & 31, l5 = (lane >> 5) & 1;
    const int kcol = 32 * wn + l31;          // this lane's k-code (0..63)

    if (t < 128) diffv[t] = xhat[b * 128 + t] - x[b * 128 + t];

    // Build Zh/Zl = split(z0[k0+k] + u[b])  (coalesced)
    {
        int k = t >> 2, dq = (t & 3) * 32;
        const float* zr = z0 + (k0 + k) * 128 + dq;
        const float* ur = u + b * 128 + dq;
#pragma unroll
        for (int g = 0; g < 8; ++g) {
            float4 a = *(const float4*)(zr + 4 * g);
            float4 c = *(const float4*)(ur + 4 * g);
            float v0 = a.x + c.x, v1 = a.y + c.y, v2 = a.z + c.z, v3 = a.w + c.w;
            ushort4 hv, lv;
            hv.x = f2bh(v0); lv.x = f2bh(v0 - bh2f(hv.x));
            hv.y = f2bh(v1); lv.y = f2bh(v1 - bh2f(hv.y));
            hv.z = f2bh(v2); lv.z = f2bh(v2 - bh2f(hv.z));
            hv.w = f2bh(v3); lv.w = f2bh(v3 - bh2f(hv.w));
            *(ushort4*)&Zh[k][dq + 4 * g] = hv;
            *(ushort4*)&Zl[k][dq + 4 * g] = lv;
        }
    }
    __syncthreads();

    // z-state C-fragments (f32): zs[mi] covers d-tile (2*wm+mi), k-tile wn.
    // C/D layout: col k = kcol, row d = 32*mt + (reg&3) + 8*(reg>>2) + 4*l5.
    f32x16 zs[2];
#pragma unroll
    for (int mi = 0; mi < 2; ++mi) {
#pragma unroll
        for (int rg = 0; rg < 4; ++rg) {
            int d0 = 32 * (2 * wm + mi) + 8 * rg + 4 * l5;
            ushort4 hv = *(const ushort4*)&Zh[kcol][d0];
            ushort4 lv = *(const ushort4*)&Zl[kcol][d0];
            zs[mi][4 * rg + 0] = bh2f(hv.x) + bh2f(lv.x);
            zs[mi][4 * rg + 1] = bh2f(hv.y) + bh2f(lv.y);
            zs[mi][4 * rg + 2] = bh2f(hv.z) + bh2f(lv.z);
            zs[mi][4 * rg + 3] = bh2f(hv.w) + bh2f(lv.w);
        }
    }

    const uint4* W1f = W1f0;
    const uint4* W2f = W2f0;
#pragma unroll 1
    for (int blk = 0; blk < 2; ++blk) {
#pragma unroll 1
        for (int c = 0; c < 4; ++c) {
            // ---- GEMM1 chunk: hT[64c..64c+63][k] = W1 . zT ----
            f32x16 acc;
#pragma unroll
            for (int r = 0; r < 16; ++r) acc[r] = 0.f;
            const int mtg = 2 * c + wm;   // W1 m-tile (h dim)
#pragma unroll 2
            for (int kt = 0; kt < 8; ++kt) {
                int d0 = 16 * kt + 8 * l5;
                uint4 bh = *(const uint4*)&Zh[kcol][d0];
                uint4 bl = *(const uint4*)&Zl[kcol][d0];
                const uint4* pa = W1f + ((mtg * 8 + kt) * 2) * 64;
                uint4 ah = pa[lane];
                uint4 al = pa[64 + lane];
                acc = mfma_bf(ah, bh, acc);
                acc = mfma_bf(ah, bl, acc);
                acc = mfma_bf(al, bh, acc);
            }
            // relu + split -> H (h-local row = 32*wm + off)
#pragma unroll
            for (int rg = 0; rg < 4; ++rg) {
                int h0 = 32 * wm + 8 * rg + 4 * l5;
                float v0 = fmaxf(acc[4 * rg + 0], 0.f);
                float v1 = fmaxf(acc[4 * rg + 1], 0.f);
                float v2 = fmaxf(acc[4 * rg + 2], 0.f);
                float v3 = fmaxf(acc[4 * rg + 3], 0.f);
                ushort4 hv, lv;
                hv.x = f2bh(v0); lv.x = f2bh(v0 - bh2f(hv.x));
                hv.y = f2bh(v1); lv.y = f2bh(v1 - bh2f(hv.y));
                hv.z = f2bh(v2); lv.z = f2bh(v2 - bh2f(hv.z));
                hv.w = f2bh(v3); lv.w = f2bh(v3 - bh2f(hv.w));
                *(ushort4*)&Hh[kcol][h0] = hv;
                *(ushort4*)&Hl[kcol][h0] = lv;
            }
            __syncthreads();
            // ---- GEMM2 chunk: zs += W2 . hT_chunk ----
#pragma unroll 2
            for (int ktl = 0; ktl < 4; ++ktl) {
                int hh0 = 16 * ktl + 8 * l5;
                uint4 bh = *(const uint4*)&Hh[kcol][hh0];
                uint4 bl = *(const uint4*)&Hl[kcol][hh0];
#pragma unroll
                for (int mi = 0; mi < 2; ++mi) {
                    const uint4* pa = W2f + (((2 * wm + mi) * 16 + (4 * c + ktl)) * 2) * 64;
                    uint4 ah = pa[lane];
                    uint4 al = pa[64 + lane];
                    zs[mi] = mfma_bf(ah, bh, zs[mi]);
                    zs[mi] = mfma_bf(ah, bl, zs[mi]);
                    zs[mi] = mfma_bf(al, bh, zs[mi]);
                }
            }
            __syncthreads();   // H free for next chunk
        }
        if (blk == 0) {
            // rebuild Zh/Zl from updated z-state for block 1's GEMM1
#pragma unroll
            for (int mi = 0; mi < 2; ++mi) {
#pragma unroll
                for (int rg = 0; rg < 4; ++rg) {
                    int d0 = 32 * (2 * wm + mi) + 8 * rg + 4 * l5;
                    float v0 = zs[mi][4 * rg + 0], v1 = zs[mi][4 * rg + 1];
                    float v2 = zs[mi][4 * rg + 2], v3 = zs[mi][4 * rg + 3];
                    ushort4 hv, lv;
                    hv.x = f2bh(v0); lv.x = f2bh(v0 - bh2f(hv.x));
                    hv.y = f2bh(v1); lv.y = f2bh(v1 - bh2f(hv.y));
                    hv.z = f2bh(v2); lv.z = f2bh(v2 - bh2f(hv.z));
                    hv.w = f2bh(v3); lv.w = f2bh(v3 - bh2f(hv.w));
                    *(ushort4*)&Zh[kcol][d0] = hv;
                    *(ushort4*)&Zl[kcol][d0] = lv;
                }
            }
            __syncthreads();
            W1f = W1f1;
            W2f = W2f1;
        }
    }

    // ---- dist from z-state ----
    float sacc = 0.f;
#pragma unroll
    for (int mi = 0; mi < 2; ++mi) {
#pragma unroll
        for (int rg = 0; rg < 4; ++rg) {
            int d0 = 32 * (2 * wm + mi) + 8 * rg + 4 * l5;
            float4 dv = *(const float4*)&diffv[d0];
            float v;
            v = zs[mi][4 * rg + 0] + dv.x; sacc = fmaf(v, v, sacc);
            v = zs[mi][4 * rg + 1] + dv.y; sacc = fmaf(v, v, sacc);
            v = zs[mi][4 * rg + 2] + dv.z; sacc = fmaf(v, v, sacc);
            v = zs[mi][4 * rg + 3] + dv.w; sacc = fmaf(v, v, sacc);
        }
    }
    sacc += __shfl_xor(sacc, 32, 64);
    if (lane < 32) part[wm][kcol] = sacc;
    __syncthreads();
    if (t < 64) dist[b * 256 + k0 + t] = part[0][t] + part[1][t];
}

// ---------------- argmin + winner recompute (unchanged, f32-exact) ----------------

__global__ __launch_bounds__(256) void k_argmin(
    const float* __restrict__ dist, int* __restrict__ codes,
    float* __restrict__ out0)
{
    __shared__ float sv[256];
    __shared__ int   si[256];
    const int t = threadIdx.x, b = blockIdx.x;
    sv[t] = dist[b * 256 + t]; si[t] = t;
    __syncthreads();
    for (int s = 128; s > 0; s >>= 1) {
        if (t < s) {
            float v2 = sv[t + s]; int i2 = si[t + s];
            if (v2 < sv[t] || (v2 == sv[t] && i2 < si[t])) { sv[t] = v2; si[t] = i2; }
        }
        __syncthreads();
    }
    if (t == 0) { codes[b] = si[0]; out0[b] = (float)si[0]; }
}

__global__ __launch_bounds__(256) void k_final(
    const float* __restrict__ z0, const float* __restrict__ u,
    const int* __restrict__ codes,
    const float* __restrict__ W1Ta, const float* __restrict__ W2Ta,
    const float* __restrict__ W1Tb, const float* __restrict__ W2Tb,
    float* __restrict__ outd)
{
    __shared__ float z8[8][128];
    __shared__ float h8[8][256];
    __shared__ int ci[8];
    const int t = threadIdx.x;
    const int b0 = blockIdx.x * 8;
    if (t < 8) ci[t] = codes[b0 + t];
    __syncthreads();
#pragma unroll
    for (int n = 0; n < 4; ++n) {
        int e = n * 256 + t; int r = e >> 7, d = e & 127;
        z8[r][d] = z0[ci[r] * 128 + d] + u[(b0 + r) * 128 + d];
    }
    __syncthreads();
    const float* W1T = W1Ta; const float* W2T = W2Ta;
#pragma unroll 1
    for (int blk = 0; blk < 2; ++blk) {
        float a1[8] = {0.f,0.f,0.f,0.f,0.f,0.f,0.f,0.f};
        for (int d = 0; d < 128; ++d) {
            const float w = W1T[d * 256 + t];
#pragma unroll
            for (int r = 0; r < 8; ++r) a1[r] = fmaf(z8[r][d], w, a1[r]);
        }
#pragma unroll
        for (int r = 0; r < 8; ++r) h8[r][t] = fmaxf(a1[r], 0.f);
        __syncthreads();
        const int ig = t & 127, rg = (t >> 7) * 4;
        float a2[4] = {0.f,0.f,0.f,0.f};
        for (int h = 0; h < 256; ++h) {
            const float w = W2T[h * 128 + ig];
#pragma unroll
            for (int j = 0; j < 4; ++j) a2[j] = fmaf(h8[rg + j][h], w, a2[j]);
        }
        __syncthreads();
#pragma unroll
        for (int j = 0; j < 4; ++j) z8[rg + j][ig] += a2[j];
        __syncthreads();
        W1T = W1Tb; W2T = W2Tb;
    }
#pragma unroll
    for (int n = 0; n < 4; ++n) {
        int e = n * 256 + t; int r = e >> 7, d = e & 127;
        outd[(b0 + r) * 128 + d] = z8[r][d];
    }
}

extern "C" void kernel_launch(void* const* d_in, const int* in_sizes, int n_in,
                              void* d_out, int out_size, void* d_ws, size_t ws_size,
                              hipStream_t stream) {
    const float* xhat = (const float*)d_in[0];
    const float* x    = (const float*)d_in[1];
    const float* cb   = (const float*)d_in[2];
    const float* Wc   = (const float*)d_in[3];
    const float* bc   = (const float*)d_in[4];
    const float* W1_0 = (const float*)d_in[5];
    const float* W2_0 = (const float*)d_in[6];
    const float* W1_1 = (const float*)d_in[7];
    const float* W2_1 = (const float*)d_in[8];
    float* out = (float*)d_out;
    float* ws  = (float*)d_ws;

    float* WzT  = ws + 0;
    float* WxT  = ws + 16384;
    float* W1T0 = ws + 32768;
    float* W2T0 = ws + 65536;
    float* W1T1 = ws + 98304;
    float* W2T1 = ws + 131072;
    float* z0   = ws + 163840;
    float* u    = ws + 196608;
    float* dist = ws + 458752;
    int*   codes = (int*)(ws + 983040);
    uint4* F    = (uint4*)(ws + 985088);   // 32768 uint4 = 512 KB
    const uint4* W1f0 = F;
    const uint4* W2f0 = F + 8192;
    const uint4* W1f1 = F + 16384;
    const uint4* W2f1 = F + 24576;

    k_transpose<<<640, 256, 0, stream>>>(Wc, W1_0, W2_0, W1_1, W2_1,
                                         WzT, WxT, W1T0, W2T0, W1T1, W2T1);
    k_pack<<<64, 256, 0, stream>>>(W1_0, W2_0, W1_1, W2_1, F);
    k_z0<<<128, 256, 0, stream>>>(cb, bc, WzT, z0);
    k_u<<<1024, 256, 0, stream>>>(xhat, WxT, u);
    k_dist_mfma<<<8192, 256, 0, stream>>>(z0, u, xhat, x, W1f0, W2f0, W1f1, W2f1, dist);
    k_argmin<<<2048, 256, 0, stream>>>(dist, codes, out);
    k_final<<<256, 256, 0, stream>>>(z0, u, codes, W1T0, W2T0, W1T1, W2T1, out + 2048);
}